// Round 3
// baseline (123.076 us; speedup 1.0000x reference)
//
#include <hip/hip_runtime.h>

// log2-domain "log 0": exp2(-30000) == 0, exactly representable in half, never NaN.
#define NEG2 (-30000.0f)
#define L2E  1.4426950408889634f
#define LN2  0.6931471805599453f

constexpr int B = 8, T = 128, U = 64, U1 = 65, V = 512;
constexpr int PDROWS = 200;          // diag rows per b (need up to dmax+4 = 195)
constexpr int PDW = PDROWS * 64;     // half2-words per b

// workspace layout (float units)
constexpr int ETH_F = 0;                            // exp(trans-mt) f16: B*T*V halves
constexpr int EPH_F = ETH_F + (B * T * V) / 2;      // exp(pred-mp) f16: B*U1*V halves
constexpr int MT_F  = EPH_F + (B * U1 * V) / 2;     // row max trans: B*T f32
constexpr int MP_F  = MT_F + B * T;                 // row max pred:  B*U1 f32
constexpr int T0_F  = MP_F + B * U1;                // trans[.,0]: B*T f32
constexpr int P0_F  = T0_F + B * T;                 // pred[.,0]:  B*U1 f32
constexpr int PL_F  = P0_F + B * U1;                // pred[u][labels[u]]: B*U1 f32
constexpr int C0_F  = PL_F + B * U1;                // blank~[t][0] col (log2): B*T f32
constexpr int TL_F  = C0_F + B * T;                 // trans[t][labels[u]] f16: B*T*64 halves
constexpr int PD_F  = TL_F + (B * T * 64) / 2;      // diag half2 lattice: B*PDW words
// Pd word (d,l): x = blank~[d-l-2][l+1], y = lab~[d-l-1][l]  (both log2-domain)

typedef _Float16 half_t;
typedef _Float16 v4h __attribute__((ext_vector_type(4)));
typedef _Float16 v8h __attribute__((ext_vector_type(8)));
typedef float    v4f __attribute__((ext_vector_type(4)));

__device__ __forceinline__ float wave_shr1(float x) {  // lane i <- lane i-1 (lane0 keeps own)
    int v = __float_as_int(x);
    int r = __builtin_amdgcn_update_dpp(v, v, 0x138, 0xF, 0xF, false); // wave_shr:1
    return __int_as_float(r);
}

// ---------------- k1: row max + exp (f16 out) + gather precomputes + zero out ----------------
__global__ __launch_bounds__(256) void k_prep(const float* __restrict__ trans,
                                              const float* __restrict__ pred,
                                              const int* __restrict__ labels,
                                              float* __restrict__ ws,
                                              float* __restrict__ out) {
    if (blockIdx.x == 0 && threadIdx.x == 0) out[0] = 0.0f;
    const int wave = (blockIdx.x * blockDim.x + threadIdx.x) >> 6;
    const int lane = threadIdx.x & 63;
    const int nrows_t = B * T;              // 1024 trans rows
    const int nrows = nrows_t + B * U1;     // + 520 pred rows
    if (wave >= nrows) return;

    const float* src; half_t* dst;
    if (wave < nrows_t) {
        src = trans + (size_t)wave * V;
        dst = (half_t*)(ws + ETH_F) + (size_t)wave * V;
    } else {
        const int r = wave - nrows_t;
        src = pred + (size_t)r * V;
        dst = (half_t*)(ws + EPH_F) + (size_t)r * V;
    }

    const float4 a = ((const float4*)src)[lane];
    const float4 c = ((const float4*)src)[lane + 64];
    float m = fmaxf(fmaxf(fmaxf(a.x, a.y), fmaxf(a.z, a.w)),
                    fmaxf(fmaxf(c.x, c.y), fmaxf(c.z, c.w)));
    #pragma unroll
    for (int off = 32; off >= 1; off >>= 1) m = fmaxf(m, __shfl_xor(m, off));

    v4h h0 = { (half_t)__expf(a.x - m), (half_t)__expf(a.y - m),
               (half_t)__expf(a.z - m), (half_t)__expf(a.w - m) };
    v4h h1 = { (half_t)__expf(c.x - m), (half_t)__expf(c.y - m),
               (half_t)__expf(c.z - m), (half_t)__expf(c.w - m) };
    ((v4h*)dst)[lane]      = h0;
    ((v4h*)dst)[lane + 64] = h1;

    if (wave < nrows_t) {                   // trans row (b,t)
        const int b = wave >> 7;
        const int lbl = labels[b * U + lane];                 // lane == u, U==64
        ((half_t*)(ws + TL_F))[(size_t)wave * 64 + lane] = (half_t)src[lbl];
        if (lane == 0) { ws[MT_F + wave] = m; ws[T0_F + wave] = a.x; }
    } else {                                // pred row (b,u)
        const int r = wave - nrows_t;
        if (lane == 0) {
            const int b = r / U1, u = r % U1;
            ws[MP_F + r] = m; ws[P0_F + r] = a.x;
            if (u < U) ws[PL_F + r] = src[labels[b * U + u]];
        }
    }
}

// ---------------- k2: MFMA f16 joint GEMM + log2 epilogue into diagonal layout ----------------
// 320 waves = 8 b x 8 t-tiles x 5 u-tiles; each wave one 16x16 C tile, K=512.
__global__ __launch_bounds__(256) void k_joint(const int* __restrict__ label_lens,
                                               float* __restrict__ ws) {
    const int lane = threadIdx.x & 63;
    const int wid = blockIdx.x * 4 + (threadIdx.x >> 6);   // 0..319
    const int b = wid / 40, r = wid % 40;
    const int t0 = (r / 5) * 16, u0 = (r % 5) * 16;
    const int n = lane & 15, q = lane >> 4;

    // A frag: ET[t0+n][kc + q*8 .. +8]; B frag: EP[u0+n][kc + q*8 .. +8] (B^T form)
    const v8h* A  = (const v8h*)((const half_t*)(ws + ETH_F) + ((size_t)(b * T + t0 + n)) * V);
    const int  uc = (u0 + n <= 64) ? (u0 + n) : 64;
    const v8h* Bp = (const v8h*)((const half_t*)(ws + EPH_F) + ((size_t)(b * U1 + uc)) * V);

    v4f acc = {0.f, 0.f, 0.f, 0.f};
    #pragma unroll
    for (int c = 0; c < 64; c += 4)        // 16 MFMAs, 32 halves of K each
        acc = __builtin_amdgcn_mfma_f32_16x16x32_f16(A[c + q], Bp[c + q], acc, 0, 0, 0);

    // C/D: col = lane&15 (-> u), row = q*4 + i (-> t)
    const int u = u0 + n;
    if (u > 64) return;
    const int ul = label_lens[b];
    const float mp_u = ws[MP_F + b * U1 + u];
    const float pr0  = ws[P0_F + b * U1 + u];
    const bool has_lab = (u < 64);
    const float prl = has_lab ? ws[PL_F + b * U1 + u] : 0.f;
    half_t* PdH = (half_t*)((uint*)(ws + PD_F) + (size_t)b * PDW);
    const half_t* TLh = (const half_t*)(ws + TL_F) + (size_t)(b * T) * 64;

    #pragma unroll
    for (int i = 0; i < 4; ++i) {
        const int t = t0 + q * 4 + i;
        const float mt = ws[MT_F + b * T + t];
        const float lse2 = (mt + mp_u) * L2E + __log2f(acc[i]);
        const float bl2 = (ws[T0_F + b * T + t] + pr0) * L2E - lse2;   // blank~[t][u]
        const int d = t + u + 1;
        if (u >= 1) PdH[(d * 64 + (u - 1)) * 2] = (half_t)bl2;
        else        ws[C0_F + b * T + t] = bl2;
        if (has_lab) {
            const float lb2 = (u >= ul) ? NEG2
                             : ((float)TLh[t * 64 + u] + prl) * L2E - lse2;  // lab~[t][u]
            PdH[(d * 64 + u) * 2 + 1] = (half_t)lb2;
        }
    }
}

// ---------------- k3: anti-diagonal DP, one wave per b, coalesced diag reads ----------------
__global__ __launch_bounds__(64) void k_dp(const float* __restrict__ ws,
                                           const int* __restrict__ act_lens,
                                           const int* __restrict__ label_lens,
                                           float* __restrict__ out) {
    const int b = blockIdx.x, l = threadIdx.x;
    __shared__ float af[T];                 // alpha~[t][0] column

    const float* c0 = ws + C0_F + b * T;
    float x0 = c0[l], x1 = c0[64 + l];
    #pragma unroll
    for (int off = 1; off < 64; off <<= 1) { float y = __shfl_up(x0, off); if (l >= off) x0 += y; }
    #pragma unroll
    for (int off = 1; off < 64; off <<= 1) { float y = __shfl_up(x1, off); if (l >= off) x1 += y; }
    const float tot = __shfl(x0, 63);
    if (l == 0) af[0] = 0.0f;
    af[l + 1] = x0;                         // t = 1..64
    if (l < 63) af[65 + l] = tot + x1;      // t = 65..127
    __syncthreads();

    const uint* Pd = (const uint*)(ws + PD_F) + (size_t)b * PDW;
    const int tl = act_lens[b] - 1;         // >= 63
    const int ul = label_lens[b];           // in [32,64]
    const int dmax = tl + ul;               // <= 191

    uint wbuf[4]; float abuf[4];            // 4-deep prefetch (covers ~L2 latency)
    #pragma unroll
    for (int j = 0; j < 4; ++j) { wbuf[j] = Pd[(1 + j) * 64 + l]; abuf[j] = af[j]; }

    float cur = 0.0f;                       // lane l owns u = l+1; steps t = d-l-1
    for (int d = 1; d <= dmax; ++d) {
        const int j = (d - 1) & 3;
        const uint w = wbuf[j];
        const float a00 = abuf[j];          // af[d-1] (alpha[t][0] for lane 0)
        const int dp = (d + 4 < PDROWS) ? d + 4 : PDROWS - 1;
        wbuf[j] = Pd[dp * 64 + l];
        abuf[j] = af[(d + 3 < T) ? d + 3 : T - 1];

        const int t = d - l - 1;
        union { uint u; half_t h[2]; } cv; cv.u = w;
        const float bn = (float)cv.h[0];    // blank~[t-1][u]
        const float lb = (float)cv.h[1];    // lab~[t][u-1]

        const float sh = wave_shr1(cur);
        const float lv = (l == 0) ? a00 : sh;        // alpha[t][u-1]
        const float a2 = lv + lb;
        const float a1 = (t >= 1) ? cur + bn : NEG2;
        const float m  = fmaxf(a1, a2);
        const float nc = m + __log2f(exp2f(a1 - m) + exp2f(a2 - m));
        cur = ((t >= 0) && (t <= tl)) ? nc : cur;
    }

    if (l == ul - 1) {                      // cur == alpha~[tl][ul]
        union { uint u; half_t h[2]; } cv; cv.u = Pd[(dmax + 1) * 64 + (ul - 1)];
        atomicAdd(out, -((cur + (float)cv.h[0]) * LN2));
    }
}

extern "C" void kernel_launch(void* const* d_in, const int* in_sizes, int n_in,
                              void* d_out, int out_size, void* d_ws, size_t ws_size,
                              hipStream_t stream) {
    const float* trans      = (const float*)d_in[0];
    const float* pred       = (const float*)d_in[1];
    const int*   labels     = (const int*)d_in[2];
    const int*   act_lens   = (const int*)d_in[3];
    const int*   label_lens = (const int*)d_in[4];
    float* ws  = (float*)d_ws;
    float* out = (float*)d_out;

    const int nrows = B * T + B * U1;                       // 1544 waves
    k_prep<<<(nrows + 3) / 4, 256, 0, stream>>>(trans, pred, labels, ws, out);
    k_joint<<<80, 256, 0, stream>>>(label_lens, ws);
    k_dp<<<8, 64, 0, stream>>>(ws, act_lens, label_lens, out);
}

// Round 4
// 85.663 us; speedup vs baseline: 1.4367x; 1.4367x over previous
//
#include <hip/hip_runtime.h>

// log2-domain "log 0": exp2(-30000) == 0, exactly representable in half, never NaN.
#define NEG2 (-30000.0f)
#define L2E  1.4426950408889634f
#define LN2  0.6931471805599453f

constexpr int B = 8, T = 128, U = 64, U1 = 65, V = 512;
constexpr int PDROWS = 200;          // diag rows per b (need up to dmax+1 = 192)
constexpr int PDW = PDROWS * 64;     // half2-words per b

// workspace layout (float units)
constexpr int ETH_F = 0;                            // exp(trans-mt) f16: B*T*V halves
constexpr int EPH_F = ETH_F + (B * T * V) / 2;      // exp(pred-mp) f16: B*U1*V halves
constexpr int MT_F  = EPH_F + (B * U1 * V) / 2;     // row max trans: B*T f32
constexpr int MP_F  = MT_F + B * T;                 // row max pred:  B*U1 f32
constexpr int T0_F  = MP_F + B * U1;                // trans[.,0]: B*T f32
constexpr int P0_F  = T0_F + B * T;                 // pred[.,0]:  B*U1 f32
constexpr int PL_F  = P0_F + B * U1;                // pred[u][labels[u]]: B*U1 f32
constexpr int C0_F  = PL_F + B * U1;                // blank~[t][0] col (log2): B*T f32
constexpr int TL_F  = C0_F + B * T;                 // trans[t][labels[u]] f16: B*T*64 halves
constexpr int PD_F  = TL_F + (B * T * 64) / 2;      // diag half2 lattice: B*PDW words
// Pd word (d,l): x = blank~[d-l-2][l+1], y = lab~[d-l-1][l]  (both log2-domain)

typedef _Float16 half_t;
typedef _Float16 v4h __attribute__((ext_vector_type(4)));
typedef _Float16 v8h __attribute__((ext_vector_type(8)));
typedef float    v4f __attribute__((ext_vector_type(4)));

__device__ __forceinline__ float wave_shr1(float x) {  // lane i <- lane i-1 (lane0 keeps own)
    int v = __float_as_int(x);
    int r = __builtin_amdgcn_update_dpp(v, v, 0x138, 0xF, 0xF, false); // wave_shr:1
    return __int_as_float(r);
}

// ---------------- k1: row max + exp (f16 out) + gather precomputes + zero out ----------------
__global__ __launch_bounds__(256) void k_prep(const float* __restrict__ trans,
                                              const float* __restrict__ pred,
                                              const int* __restrict__ labels,
                                              float* __restrict__ ws,
                                              float* __restrict__ out) {
    if (blockIdx.x == 0 && threadIdx.x == 0) out[0] = 0.0f;
    const int wave = (blockIdx.x * blockDim.x + threadIdx.x) >> 6;
    const int lane = threadIdx.x & 63;
    const int nrows_t = B * T;              // 1024 trans rows
    const int nrows = nrows_t + B * U1;     // + 520 pred rows
    if (wave >= nrows) return;

    const float* src; half_t* dst;
    if (wave < nrows_t) {
        src = trans + (size_t)wave * V;
        dst = (half_t*)(ws + ETH_F) + (size_t)wave * V;
    } else {
        const int r = wave - nrows_t;
        src = pred + (size_t)r * V;
        dst = (half_t*)(ws + EPH_F) + (size_t)r * V;
    }

    const float4 a = ((const float4*)src)[lane];
    const float4 c = ((const float4*)src)[lane + 64];
    float m = fmaxf(fmaxf(fmaxf(a.x, a.y), fmaxf(a.z, a.w)),
                    fmaxf(fmaxf(c.x, c.y), fmaxf(c.z, c.w)));
    #pragma unroll
    for (int off = 32; off >= 1; off >>= 1) m = fmaxf(m, __shfl_xor(m, off));

    v4h h0 = { (half_t)__expf(a.x - m), (half_t)__expf(a.y - m),
               (half_t)__expf(a.z - m), (half_t)__expf(a.w - m) };
    v4h h1 = { (half_t)__expf(c.x - m), (half_t)__expf(c.y - m),
               (half_t)__expf(c.z - m), (half_t)__expf(c.w - m) };
    ((v4h*)dst)[lane]      = h0;
    ((v4h*)dst)[lane + 64] = h1;

    if (wave < nrows_t) {                   // trans row (b,t)
        const int b = wave >> 7;
        const int lbl = labels[b * U + lane];                 // lane == u, U==64
        ((half_t*)(ws + TL_F))[(size_t)wave * 64 + lane] = (half_t)src[lbl];
        if (lane == 0) { ws[MT_F + wave] = m; ws[T0_F + wave] = a.x; }
    } else {                                // pred row (b,u)
        const int r = wave - nrows_t;
        if (lane == 0) {
            const int b = r / U1, u = r % U1;
            ws[MP_F + r] = m; ws[P0_F + r] = a.x;
            if (u < U) ws[PL_F + r] = src[labels[b * U + u]];
        }
    }
}

// ---------------- k2: MFMA f16 joint GEMM + log2 epilogue into diagonal layout ----------------
// 320 waves = 8 b x 8 t-tiles x 5 u-tiles; each wave one 16x16 C tile, K=512.
__global__ __launch_bounds__(256) void k_joint(const int* __restrict__ label_lens,
                                               float* __restrict__ ws) {
    const int lane = threadIdx.x & 63;
    const int wid = blockIdx.x * 4 + (threadIdx.x >> 6);   // 0..319
    const int b = wid / 40, r = wid % 40;
    const int t0 = (r / 5) * 16, u0 = (r % 5) * 16;
    const int n = lane & 15, q = lane >> 4;

    // A frag: ET[t0+n][kc + q*8 .. +8]; B frag: EP[u0+n][kc + q*8 .. +8] (B^T form)
    const v8h* A  = (const v8h*)((const half_t*)(ws + ETH_F) + ((size_t)(b * T + t0 + n)) * V);
    const int  uc = (u0 + n <= 64) ? (u0 + n) : 64;
    const v8h* Bp = (const v8h*)((const half_t*)(ws + EPH_F) + ((size_t)(b * U1 + uc)) * V);

    v4f acc = {0.f, 0.f, 0.f, 0.f};
    #pragma unroll
    for (int c = 0; c < 64; c += 4)        // 16 MFMAs, 32 halves of K each
        acc = __builtin_amdgcn_mfma_f32_16x16x32_f16(A[c + q], Bp[c + q], acc, 0, 0, 0);

    // C/D: col = lane&15 (-> u), row = q*4 + i (-> t)
    const int u = u0 + n;
    if (u > 64) return;
    const int ul = label_lens[b];
    const float mp_u = ws[MP_F + b * U1 + u];
    const float pr0  = ws[P0_F + b * U1 + u];
    const bool has_lab = (u < 64);
    const float prl = has_lab ? ws[PL_F + b * U1 + u] : 0.f;
    half_t* PdH = (half_t*)((uint*)(ws + PD_F) + (size_t)b * PDW);
    const half_t* TLh = (const half_t*)(ws + TL_F) + (size_t)(b * T) * 64;

    #pragma unroll
    for (int i = 0; i < 4; ++i) {
        const int t = t0 + q * 4 + i;
        const float mt = ws[MT_F + b * T + t];
        const float lse2 = (mt + mp_u) * L2E + __log2f(acc[i]);
        const float bl2 = (ws[T0_F + b * T + t] + pr0) * L2E - lse2;   // blank~[t][u]
        const int d = t + u + 1;
        if (u >= 1) PdH[(d * 64 + (u - 1)) * 2] = (half_t)bl2;
        else        ws[C0_F + b * T + t] = bl2;
        if (has_lab) {
            const float lb2 = (u >= ul) ? NEG2
                             : ((float)TLh[t * 64 + u] + prl) * L2E - lse2;  // lab~[t][u]
            PdH[(d * 64 + u) * 2 + 1] = (half_t)lb2;
        }
    }
}

// ---------------- k3: anti-diagonal DP, one wave per b ----------------
// Fixed 192-iteration loop (no-op beyond dmax via the t<=tl guard) so #pragma unroll
// keeps the prefetch rotation in REGISTERS (round-3 bug: dynamic index -> scratch, VGPR=12).
__global__ __launch_bounds__(64) void k_dp(const float* __restrict__ ws,
                                           const int* __restrict__ act_lens,
                                           const int* __restrict__ label_lens,
                                           float* __restrict__ out) {
    const int b = blockIdx.x, l = threadIdx.x;

    constexpr int DROWS = 192;                 // diag rows 1..192 staged at idx d-1
    __shared__ uint Pds[DROWS * 64];           // 48 KB
    __shared__ float af[T];                    // alpha~[t][0] column

    // ---- stage diag lattice rows 1..192 (one burst, coalesced uint4) ----
    const uint4* src4 = (const uint4*)((const uint*)(ws + PD_F) + (size_t)b * PDW + 64);
    uint4* dst4 = (uint4*)Pds;
    #pragma unroll
    for (int i = 0; i < DROWS / 4; ++i)        // 48 iters: lane-contiguous 16B chunks
        dst4[i * 64 + l] = src4[i * 64 + l];

    // ---- alpha0 column: inclusive prefix scan of C0 (128 values, 2 per lane) ----
    const float* c0 = ws + C0_F + b * T;
    float x0 = c0[l], x1 = c0[64 + l];
    #pragma unroll
    for (int off = 1; off < 64; off <<= 1) { float y = __shfl_up(x0, off); if (l >= off) x0 += y; }
    #pragma unroll
    for (int off = 1; off < 64; off <<= 1) { float y = __shfl_up(x1, off); if (l >= off) x1 += y; }
    const float tot = __shfl(x0, 63);
    if (l == 0) af[0] = 0.0f;
    af[l + 1] = x0;                            // t = 1..64
    if (l < 63) af[65 + l] = tot + x1;         // t = 65..127
    __syncthreads();

    const int tl = act_lens[b] - 1;            // >= 63
    const int ul = label_lens[b];              // in [32,64]
    const int dmax = tl + ul;                  // <= 191

    // ---- DP: lane l owns u = l+1; at step d, t = d-l-1 ----
    uint wb[4]; float ab[4];                   // depth-4 prefetch, register-resident
    #pragma unroll
    for (int j = 0; j < 4; ++j) { wb[j] = Pds[j * 64 + l]; ab[j] = af[j]; }

    float cur = 0.0f;
    #pragma unroll
    for (int d = 1; d <= DROWS; ++d) {         // compile-time trip count -> full unroll
        const int j = (d - 1) & 3;
        const uint w = wb[j];
        const float a00 = ab[j];               // af[d-1]
        const int pr = (d + 3 < DROWS) ? d + 3 : DROWS - 1;
        wb[j] = Pds[pr * 64 + l];
        ab[j] = af[(d + 3 < T) ? d + 3 : T - 1];

        const int t = d - l - 1;
        union { uint u; half_t h[2]; } cv; cv.u = w;
        const float bn = (float)cv.h[0];       // blank~[t-1][u]
        const float lb = (float)cv.h[1];       // lab~[t][u-1]

        const float sh = wave_shr1(cur);
        const float lv = (l == 0) ? a00 : sh;  // alpha[t][u-1]
        const float a2 = lv + lb;
        const float a1 = (t >= 1) ? cur + bn : NEG2;
        const float m  = fmaxf(a1, a2);
        const float nc = m + __log2f(exp2f(a1 - m) + exp2f(a2 - m));
        cur = ((t >= 0) && (t <= tl)) ? nc : cur;
    }

    if (l == ul - 1) {                         // cur == alpha~[tl][ul]
        union { uint u; half_t h[2]; } cv; cv.u = Pds[dmax * 64 + (ul - 1)]; // row dmax+1
        atomicAdd(out, -((cur + (float)cv.h[0]) * LN2));
    }
}

extern "C" void kernel_launch(void* const* d_in, const int* in_sizes, int n_in,
                              void* d_out, int out_size, void* d_ws, size_t ws_size,
                              hipStream_t stream) {
    const float* trans      = (const float*)d_in[0];
    const float* pred       = (const float*)d_in[1];
    const int*   labels     = (const int*)d_in[2];
    const int*   act_lens   = (const int*)d_in[3];
    const int*   label_lens = (const int*)d_in[4];
    float* ws  = (float*)d_ws;
    float* out = (float*)d_out;

    const int nrows = B * T + B * U1;                       // 1544 waves
    k_prep<<<(nrows + 3) / 4, 256, 0, stream>>>(trans, pred, labels, ws, out);
    k_joint<<<80, 256, 0, stream>>>(label_lens, ws);
    k_dp<<<8, 64, 0, stream>>>(ws, act_lens, label_lens, out);
}